// Round 1
// baseline (570.963 us; speedup 1.0000x reference)
//
#include <hip/hip_runtime.h>

typedef unsigned short u16;
typedef short short8 __attribute__((ext_vector_type(8)));
typedef float floatx4 __attribute__((ext_vector_type(4)));

#define TT 2048
#define CC 1024

__device__ __forceinline__ u16 f2bf(float f) {
  unsigned int u = __float_as_uint(f);
  u += 0x7fffu + ((u >> 16) & 1u);
  return (u16)(u >> 16);
}

// ---------------- fp32 -> bf16 convert (weights) ----------------
__global__ __launch_bounds__(256) void cvt_bf16_kernel(const float* __restrict__ in,
                                                       u16* __restrict__ out) {
  int i = blockIdx.x * blockDim.x + threadIdx.x;
  float4 v = ((const float4*)in)[i];
  ushort4 o;
  o.x = f2bf(v.x); o.y = f2bf(v.y); o.z = f2bf(v.z); o.w = f2bf(v.w);
  ((ushort4*)out)[i] = o;
}

// ---------------- LayerNorm (unbiased std, /(std+eps)) -> bf16 ----------------
__global__ __launch_bounds__(256) void ln_kernel(const float* __restrict__ x,
                                                 const float* __restrict__ g,
                                                 const float* __restrict__ b,
                                                 u16* __restrict__ out) {
  int row = blockIdx.x;
  int tid = threadIdx.x;
  const float4* xr = (const float4*)(x + (size_t)row * CC);
  float4 v = xr[tid];
  float s = v.x + v.y + v.z + v.w;
  float sq = v.x * v.x + v.y * v.y + v.z * v.z + v.w * v.w;
#pragma unroll
  for (int off = 1; off < 64; off <<= 1) {
    s += __shfl_xor(s, off);
    sq += __shfl_xor(sq, off);
  }
  __shared__ float ss[4], ssq[4];
  int wave = tid >> 6;
  if ((tid & 63) == 0) { ss[wave] = s; ssq[wave] = sq; }
  __syncthreads();
  s = ss[0] + ss[1] + ss[2] + ss[3];
  sq = ssq[0] + ssq[1] + ssq[2] + ssq[3];
  float mean = s * (1.0f / CC);
  float var = (sq - (float)CC * mean * mean) * (1.0f / (CC - 1));
  float inv = 1.0f / (sqrtf(fmaxf(var, 0.0f)) + 1e-6f);
  float4 gv = ((const float4*)g)[tid];
  float4 bv = ((const float4*)b)[tid];
  ushort4 o;
  o.x = f2bf(gv.x * (v.x - mean) * inv + bv.x);
  o.y = f2bf(gv.y * (v.y - mean) * inv + bv.y);
  o.z = f2bf(gv.z * (v.z - mean) * inv + bv.z);
  o.w = f2bf(gv.w * (v.w - mean) * inv + bv.w);
  ((ushort4*)(out + (size_t)row * CC))[tid] = o;
}

// ---------------- GEMM: out[m,n] = sum_k A[m,k] * W[n,k]  (both bf16 row-major) ----
// MODE 0: qkv epilogue -> bf16 out, scale cols<1024 by 0.125 (q pre-scale), no bias
// MODE 1: + bias + fp32 residual -> fp32 out
// MODE 2: + bias, relu -> bf16 out
template <int MODE>
__global__ __launch_bounds__(256) void gemm_bt(const u16* __restrict__ A,
                                               const u16* __restrict__ W,
                                               const float* __restrict__ bias,
                                               const float* __restrict__ resid,
                                               float* __restrict__ outf,
                                               u16* __restrict__ outb,
                                               int M, int N, int K) {
  __shared__ u16 a_lds[128][40];
  __shared__ u16 b_lds[128][40];
  int tid = threadIdx.x;
  int wave = tid >> 6, lane = tid & 63;
  int l15 = lane & 15, quad = lane >> 4;
  int wm = (wave >> 1) * 64, wn = (wave & 1) * 64;
  int tm = blockIdx.x * 128, tn = blockIdx.y * 128;
  floatx4 acc[4][4];
#pragma unroll
  for (int i = 0; i < 4; i++)
#pragma unroll
    for (int j = 0; j < 4; j++) acc[i][j] = (floatx4){0.f, 0.f, 0.f, 0.f};

  int srow = tid >> 1;
  int scol = (tid & 1) * 16;
  const u16* Ag = A + (size_t)(tm + srow) * K + scol;
  const u16* Bg = W + (size_t)(tn + srow) * K + scol;

  for (int k0 = 0; k0 < K; k0 += 32) {
    uint4 av0 = *(const uint4*)(Ag + k0);
    uint4 av1 = *(const uint4*)(Ag + k0 + 8);
    uint4 bv0 = *(const uint4*)(Bg + k0);
    uint4 bv1 = *(const uint4*)(Bg + k0 + 8);
    __syncthreads();
    *(uint4*)&a_lds[srow][scol] = av0;
    *(uint4*)&a_lds[srow][scol + 8] = av1;
    *(uint4*)&b_lds[srow][scol] = bv0;
    *(uint4*)&b_lds[srow][scol + 8] = bv1;
    __syncthreads();
    short8 af[4], bw[4];
#pragma unroll
    for (int i = 0; i < 4; i++) af[i] = *(const short8*)&a_lds[wm + i * 16 + l15][quad * 8];
#pragma unroll
    for (int j = 0; j < 4; j++) bw[j] = *(const short8*)&b_lds[wn + j * 16 + l15][quad * 8];
#pragma unroll
    for (int i = 0; i < 4; i++)
#pragma unroll
      for (int j = 0; j < 4; j++)
        acc[i][j] = __builtin_amdgcn_mfma_f32_16x16x32_bf16(af[i], bw[j], acc[i][j], 0, 0, 0);
  }

#pragma unroll
  for (int i = 0; i < 4; i++) {
    int row0 = tm + wm + i * 16 + quad * 4;
#pragma unroll
    for (int j = 0; j < 4; j++) {
      int col = tn + wn + j * 16 + l15;
      float bb = (MODE != 0) ? bias[col] : 0.0f;
#pragma unroll
      for (int r = 0; r < 4; r++) {
        int row = row0 + r;
        float v = acc[i][j][r];
        if (MODE == 0) {
          if (col < 1024) v *= 0.125f;
          outb[(size_t)row * N + col] = f2bf(v);
        } else if (MODE == 1) {
          outf[(size_t)row * N + col] = v + bb + resid[(size_t)row * N + col];
        } else {
          outb[(size_t)row * N + col] = f2bf(fmaxf(v + bb, 0.0f));
        }
      }
    }
  }
}

// ---------------- Flash attention (causal), bf16 MFMA ----------------
// qkv layout: [b*T + t][3072] bf16, q (pre-scaled by 0.125) at cols [0,1024),
// k at [1024,2048), v at [2048,3072). Block: (q-tile of 64 rows) x (b,h).
__global__ __launch_bounds__(256) void flash_kernel(const u16* __restrict__ qkv,
                                                    u16* __restrict__ attn) {
  int qt = blockIdx.x;
  int bh = blockIdx.y;
  int b = bh >> 4, h = bh & 15;
  int tid = threadIdx.x, wave = tid >> 6, lane = tid & 63;
  int l15 = lane & 15, quad = lane >> 4;
  __shared__ u16 k_lds[32][72];
  __shared__ u16 vt_lds[64][40];
  __shared__ u16 p_lds[4][16][40];

  int qrow = qt * 64 + wave * 16 + l15;
  const u16* qb = qkv + (size_t)(b * TT + qrow) * 3072 + h * 64;
  short8 qf0 = *(const short8*)(qb + quad * 8);
  short8 qf1 = *(const short8*)(qb + 32 + quad * 8);

  float m_i[4], l_i[4];
  floatx4 accO[4];
#pragma unroll
  for (int r = 0; r < 4; r++) { m_i[r] = -3.0e38f; l_i[r] = 0.0f; }
#pragma unroll
  for (int d = 0; d < 4; d++) accO[d] = (floatx4){0.f, 0.f, 0.f, 0.f};

  int kt_end = qt * 2 + 2;
  int sr = tid >> 3;
  int sc = (tid & 7) * 8;
  const u16* kg0 = qkv + (size_t)(b * TT) * 3072 + 1024 + h * 64;
  const u16* vg0 = qkv + (size_t)(b * TT) * 3072 + 2048 + h * 64;

  for (int kt = 0; kt < kt_end; kt++) {
    int s0 = kt * 32;
    uint4 kv = *(const uint4*)(kg0 + (size_t)(s0 + sr) * 3072 + sc);
    uint4 vv = *(const uint4*)(vg0 + (size_t)(s0 + sr) * 3072 + sc);
    __syncthreads();
    *(uint4*)&k_lds[sr][sc] = kv;
    u16 tmp[8];
    *(uint4*)tmp = vv;
#pragma unroll
    for (int j = 0; j < 8; j++) vt_lds[sc + j][sr] = tmp[j];
    __syncthreads();

    floatx4 s0v = (floatx4){0.f, 0.f, 0.f, 0.f};
    floatx4 s1v = (floatx4){0.f, 0.f, 0.f, 0.f};
    {
      short8 kf;
      kf = *(const short8*)&k_lds[l15][quad * 8];
      s0v = __builtin_amdgcn_mfma_f32_16x16x32_bf16(qf0, kf, s0v, 0, 0, 0);
      kf = *(const short8*)&k_lds[l15][32 + quad * 8];
      s0v = __builtin_amdgcn_mfma_f32_16x16x32_bf16(qf1, kf, s0v, 0, 0, 0);
      kf = *(const short8*)&k_lds[16 + l15][quad * 8];
      s1v = __builtin_amdgcn_mfma_f32_16x16x32_bf16(qf0, kf, s1v, 0, 0, 0);
      kf = *(const short8*)&k_lds[16 + l15][32 + quad * 8];
      s1v = __builtin_amdgcn_mfma_f32_16x16x32_bf16(qf1, kf, s1v, 0, 0, 0);
    }

    int q0 = qt * 64 + wave * 16 + quad * 4;
    float alpha[4];
#pragma unroll
    for (int r = 0; r < 4; r++) {
      int qg = q0 + r;
      float vA = ((s0 + l15) > qg) ? -3.0e38f : s0v[r];
      float vB = ((s0 + 16 + l15) > qg) ? -3.0e38f : s1v[r];
      float mx = fmaxf(vA, vB);
#pragma unroll
      for (int off = 1; off < 16; off <<= 1) mx = fmaxf(mx, __shfl_xor(mx, off));
      float mnew = fmaxf(m_i[r], mx);
      float pA = __expf(vA - mnew);
      float pB = __expf(vB - mnew);
      s0v[r] = pA;
      s1v[r] = pB;
      float ps = pA + pB;
#pragma unroll
      for (int off = 1; off < 16; off <<= 1) ps += __shfl_xor(ps, off);
      float a = __expf(m_i[r] - mnew);
      l_i[r] = l_i[r] * a + ps;
      m_i[r] = mnew;
      alpha[r] = a;
    }
#pragma unroll
    for (int d = 0; d < 4; d++) {
#pragma unroll
      for (int r = 0; r < 4; r++) accO[d][r] = accO[d][r] * alpha[r];
    }
#pragma unroll
    for (int r = 0; r < 4; r++) {
      p_lds[wave][quad * 4 + r][l15] = f2bf(s0v[r]);
      p_lds[wave][quad * 4 + r][16 + l15] = f2bf(s1v[r]);
    }
    __syncthreads();
    short8 pf = *(const short8*)&p_lds[wave][l15][quad * 8];
#pragma unroll
    for (int d = 0; d < 4; d++) {
      short8 vf = *(const short8*)&vt_lds[d * 16 + l15][quad * 8];
      accO[d] = __builtin_amdgcn_mfma_f32_16x16x32_bf16(pf, vf, accO[d], 0, 0, 0);
    }
  }

  int q0 = qt * 64 + wave * 16 + quad * 4;
#pragma unroll
  for (int r = 0; r < 4; r++) {
    float inv = 1.0f / l_i[r];
    u16* orow = attn + (size_t)(b * TT + q0 + r) * CC + h * 64;
#pragma unroll
    for (int d = 0; d < 4; d++) orow[d * 16 + l15] = f2bf(accO[d][r] * inv);
  }
}

// ---------------- launch ----------------
extern "C" void kernel_launch(void* const* d_in, const int* in_sizes, int n_in,
                              void* d_out, int out_size, void* d_ws, size_t ws_size,
                              hipStream_t stream) {
  const float* x      = (const float*)d_in[0];
  const float* qkv_w  = (const float*)d_in[1];
  const float* proj_w = (const float*)d_in[2];
  const float* proj_b = (const float*)d_in[3];
  const float* l1_w   = (const float*)d_in[4];
  const float* l1_b   = (const float*)d_in[5];
  const float* l3_w   = (const float*)d_in[6];
  const float* l3_b   = (const float*)d_in[7];
  const float* ln1_g  = (const float*)d_in[8];
  const float* ln1_b  = (const float*)d_in[9];
  const float* ln2_g  = (const float*)d_in[10];
  const float* ln2_b  = (const float*)d_in[11];
  float* out = (float*)d_out;
  char* ws = (char*)d_ws;

  u16* w_qkv  = (u16*)(ws + 0);          // 6,291,456 B
  u16* w_proj = (u16*)(ws + 6291456);    // 2,097,152 B
  u16* w_l1   = (u16*)(ws + 8388608);    // 8,388,608 B
  u16* w_l3   = (u16*)(ws + 16777216);   // 8,388,608 B
  u16* lnb    = (u16*)(ws + 25165824);   // 8,388,608 B (reused for ln1 & ln2)
  u16* qkvb   = (u16*)(ws + 33554432);   // 25,165,824 B
  u16* attnb  = (u16*)(ws + 58720256);   // 8,388,608 B
  float* x1   = (float*)(ws + 67108864); // 16,777,216 B
  u16* hb     = (u16*)(ws + 83886080);   // 33,554,432 B  (end 117,440,512)

  cvt_bf16_kernel<<<3072, 256, 0, stream>>>(qkv_w, w_qkv);
  cvt_bf16_kernel<<<1024, 256, 0, stream>>>(proj_w, w_proj);
  cvt_bf16_kernel<<<4096, 256, 0, stream>>>(l1_w, w_l1);
  cvt_bf16_kernel<<<4096, 256, 0, stream>>>(l3_w, w_l3);

  ln_kernel<<<4096, 256, 0, stream>>>(x, ln1_g, ln1_b, lnb);
  gemm_bt<0><<<dim3(32, 24), 256, 0, stream>>>(lnb, w_qkv, nullptr, nullptr, nullptr,
                                               qkvb, 4096, 3072, 1024);
  flash_kernel<<<dim3(32, 32), 256, 0, stream>>>(qkvb, attnb);
  gemm_bt<1><<<dim3(32, 8), 256, 0, stream>>>(attnb, w_proj, proj_b, x, x1, nullptr,
                                              4096, 1024, 1024);
  ln_kernel<<<4096, 256, 0, stream>>>(x1, ln2_g, ln2_b, lnb);
  gemm_bt<2><<<dim3(32, 32), 256, 0, stream>>>(lnb, w_l1, l1_b, nullptr, nullptr, hb,
                                               4096, 4096, 1024);
  gemm_bt<1><<<dim3(32, 8), 256, 0, stream>>>(hb, w_l3, l3_b, x1, out, nullptr,
                                              4096, 1024, 4096);
}

// Round 2
// 367.743 us; speedup vs baseline: 1.5526x; 1.5526x over previous
//
#include <hip/hip_runtime.h>

typedef unsigned short u16;
typedef short short8 __attribute__((ext_vector_type(8)));
typedef float floatx4 __attribute__((ext_vector_type(4)));

#define TT 2048
#define CC 1024

__device__ __forceinline__ u16 f2bf(float f) {
  unsigned int u = __float_as_uint(f);
  u += 0x7fffu + ((u >> 16) & 1u);
  return (u16)(u >> 16);
}

__device__ __forceinline__ void glds16(const u16* g, u16* l) {
  __builtin_amdgcn_global_load_lds((const __attribute__((address_space(1))) void*)g,
                                   (__attribute__((address_space(3))) void*)l, 16, 0, 0);
}

// ---------------- fp32 -> bf16 convert (weights) ----------------
__global__ __launch_bounds__(256) void cvt_bf16_kernel(const float* __restrict__ in,
                                                       u16* __restrict__ out) {
  int i = blockIdx.x * blockDim.x + threadIdx.x;
  float4 v = ((const float4*)in)[i];
  ushort4 o;
  o.x = f2bf(v.x); o.y = f2bf(v.y); o.z = f2bf(v.z); o.w = f2bf(v.w);
  ((ushort4*)out)[i] = o;
}

// ---------------- LayerNorm (unbiased std, /(std+eps)) -> bf16 ----------------
__global__ __launch_bounds__(256) void ln_kernel(const float* __restrict__ x,
                                                 const float* __restrict__ g,
                                                 const float* __restrict__ b,
                                                 u16* __restrict__ out) {
  int row = blockIdx.x;
  int tid = threadIdx.x;
  const float4* xr = (const float4*)(x + (size_t)row * CC);
  float4 v = xr[tid];
  float s = v.x + v.y + v.z + v.w;
  float sq = v.x * v.x + v.y * v.y + v.z * v.z + v.w * v.w;
#pragma unroll
  for (int off = 1; off < 64; off <<= 1) {
    s += __shfl_xor(s, off);
    sq += __shfl_xor(sq, off);
  }
  __shared__ float ss[4], ssq[4];
  int wave = tid >> 6;
  if ((tid & 63) == 0) { ss[wave] = s; ssq[wave] = sq; }
  __syncthreads();
  s = ss[0] + ss[1] + ss[2] + ss[3];
  sq = ssq[0] + ssq[1] + ssq[2] + ssq[3];
  float mean = s * (1.0f / CC);
  float var = (sq - (float)CC * mean * mean) * (1.0f / (CC - 1));
  float inv = 1.0f / (sqrtf(fmaxf(var, 0.0f)) + 1e-6f);
  float4 gv = ((const float4*)g)[tid];
  float4 bv = ((const float4*)b)[tid];
  ushort4 o;
  o.x = f2bf(gv.x * (v.x - mean) * inv + bv.x);
  o.y = f2bf(gv.y * (v.y - mean) * inv + bv.y);
  o.z = f2bf(gv.z * (v.z - mean) * inv + bv.z);
  o.w = f2bf(gv.w * (v.w - mean) * inv + bv.w);
  ((ushort4*)(out + (size_t)row * CC))[tid] = o;
}

// ---------------- GEMM (m97-style): out[m,n] = sum_k A[m,k] * W[n,k] ----------------
// BK=64, global_load_lds width-16 staging, XOR-swizzled unpadded LDS.
// MODE 0: qkv epilogue -> bf16 out, scale cols<1024 by 0.125 (q pre-scale), no bias
// MODE 1: + bias + fp32 residual -> fp32 out
// MODE 2: + bias, relu -> bf16 out
template <int MODE>
__global__ __launch_bounds__(256) void gemm_bt(const u16* __restrict__ A,
                                               const u16* __restrict__ W,
                                               const float* __restrict__ bias,
                                               const float* __restrict__ resid,
                                               float* __restrict__ outf,
                                               u16* __restrict__ outb,
                                               int M, int N, int K) {
  __shared__ u16 a_lds[8192];  // 128 rows x 64 (BK), chunk-swizzled
  __shared__ u16 b_lds[8192];
  int tid = threadIdx.x;
  int w = tid >> 6, lane = tid & 63;
  int l15 = lane & 15, quad = lane >> 4;
  int wm = (w >> 1) * 64, wn = (w & 1) * 64;
  int tm = blockIdx.x * 128, tn = blockIdx.y * 128;
  floatx4 acc[4][4];
#pragma unroll
  for (int i = 0; i < 4; i++)
#pragma unroll
    for (int j = 0; j < 4; j++) acc[i][j] = (floatx4){0.f, 0.f, 0.f, 0.f};

  // staging: wave w covers rows [w*32, w*32+32) of the 128-row tile, 4 issues of 8 rows
  int rsub = lane >> 3;              // 0..7
  int cg = (lane & 7) ^ rsub;        // global 16B-chunk index (swizzled)
  const u16* Ag = A + (size_t)(tm + w * 32 + rsub) * K + cg * 8;
  const u16* Bg = W + (size_t)(tn + w * 32 + rsub) * K + cg * 8;
  u16* aL = a_lds + w * 32 * 64;
  u16* bL = b_lds + w * 32 * 64;

  // fragment read offsets (u16 units); LDS[r][cl] holds G[r][cl ^ (r&7)]
  int x = l15 & 7;
  int offA[4], offB[4];
#pragma unroll
  for (int i = 0; i < 4; i++) offA[i] = (wm + i * 16 + l15) * 64 + ((quad ^ x) * 8);
#pragma unroll
  for (int j = 0; j < 4; j++) offB[j] = (wn + j * 16 + l15) * 64 + ((quad ^ x) * 8);

  for (int k0 = 0; k0 < K; k0 += 64) {
    __syncthreads();  // prior iter's readers done before overwrite
#pragma unroll
    for (int is = 0; is < 4; is++) glds16(Ag + k0 + is * 8 * K, aL + is * 512);
#pragma unroll
    for (int is = 0; is < 4; is++) glds16(Bg + k0 + is * 8 * K, bL + is * 512);
    __syncthreads();  // drains vmcnt -> tiles resident
#pragma unroll
    for (int s = 0; s < 2; s++) {
      short8 af[4], bw[4];
#pragma unroll
      for (int i = 0; i < 4; i++) af[i] = *(const short8*)(a_lds + (offA[i] ^ (s << 5)));
#pragma unroll
      for (int j = 0; j < 4; j++) bw[j] = *(const short8*)(b_lds + (offB[j] ^ (s << 5)));
#pragma unroll
      for (int i = 0; i < 4; i++)
#pragma unroll
        for (int j = 0; j < 4; j++)
          acc[i][j] = __builtin_amdgcn_mfma_f32_16x16x32_bf16(af[i], bw[j], acc[i][j], 0, 0, 0);
    }
  }

#pragma unroll
  for (int i = 0; i < 4; i++) {
    int row0 = tm + wm + i * 16 + quad * 4;
#pragma unroll
    for (int j = 0; j < 4; j++) {
      int col = tn + wn + j * 16 + l15;
      float bb = (MODE != 0) ? bias[col] : 0.0f;
#pragma unroll
      for (int r = 0; r < 4; r++) {
        int row = row0 + r;
        float v = acc[i][j][r];
        if (MODE == 0) {
          if (col < 1024) v *= 0.125f;
          outb[(size_t)row * N + col] = f2bf(v);
        } else if (MODE == 1) {
          outf[(size_t)row * N + col] = v + bb + resid[(size_t)row * N + col];
        } else {
          outb[(size_t)row * N + col] = f2bf(fmaxf(v + bb, 0.0f));
        }
      }
    }
  }
}

// ---------------- Flash attention (causal), S^T formulation ----------------
// qkv: [b*T + t][3072] bf16; q (pre-scaled 0.125) cols [0,1024), k [1024,2048), v [2048,3072).
// Block = 64 q-rows x (b,h); 4 waves x 16 q-rows; KV tile = 64 keys.
// S^T = mfma(A=K-frag, B=Q-frag): lane l15 = q-row m, quad*4+r (+16i) = key s.
__global__ __launch_bounds__(256) void flash_kernel(const u16* __restrict__ qkv,
                                                    u16* __restrict__ attn) {
  int bid = blockIdx.x;
  int qt = 31 - (bid >> 5);   // long blocks first
  int bh = bid & 31;
  int b = bh >> 4, h = bh & 15;
  int tid = threadIdx.x, w = tid >> 6, lane = tid & 63;
  int l15 = lane & 15, quad = lane >> 4;

  __shared__ u16 k_lds[64 * 64];        // chunk-swizzled, unpadded (global_load_lds)
  __shared__ u16 vt_lds[64 * 72];       // V^T: [d][s], stride 72
  __shared__ u16 p_lds[4][16 * 72];     // per-wave P: [m][s], stride 72

  int qbase = qt * 64 + w * 16;
  const u16* qp = qkv + (size_t)(b * TT + qbase + l15) * 3072 + h * 64;
  short8 qf0 = *(const short8*)(qp + quad * 8);
  short8 qf1 = *(const short8*)(qp + 32 + quad * 8);

  float m_i = -3.0e38f, l_i = 0.0f;
  floatx4 accO[4];
#pragma unroll
  for (int jf = 0; jf < 4; jf++) accO[jf] = (floatx4){0.f, 0.f, 0.f, 0.f};

  // K staging (global_load_lds): wave w rows [w*16, w*16+16), 2 issues of 8 rows
  int rsub = lane >> 3;
  int cg = (lane & 7) ^ rsub;
  const u16* Kg = qkv + (size_t)(b * TT + w * 16 + rsub) * 3072 + 1024 + h * 64 + cg * 8;
  u16* kL = k_lds + w * 16 * 64;
  // V staging with transpose: thread -> (s = tid&63, d0 = (tid>>6)*16)
  int sV = tid & 63, d0v = (tid >> 6) * 16;
  const u16* Vg = qkv + (size_t)(b * TT + sV) * 3072 + 2048 + h * 64 + d0v;

  int x = l15 & 7;
  int kOff[4], vOff[4];
#pragma unroll
  for (int i = 0; i < 4; i++) kOff[i] = (i * 16 + l15) * 64 + ((quad ^ x) * 8);
#pragma unroll
  for (int jf = 0; jf < 4; jf++) vOff[jf] = (jf * 16 + l15) * 72 + quad * 8;
  int pRd = l15 * 72 + quad * 8;

  int kt_end = qt + 1;
  for (int kt = 0; kt < kt_end; kt++) {
    int s0 = kt * 64;
    size_t soff = (size_t)s0 * 3072;
    uint4 v0 = *(const uint4*)(Vg + soff);
    uint4 v1 = *(const uint4*)(Vg + soff + 8);
    __syncthreads();  // prior tile's readers done
#pragma unroll
    for (int is = 0; is < 2; is++) glds16(Kg + soff + (size_t)is * 8 * 3072, kL + is * 512);
    {
      u16 tmp[16];
      *(uint4*)tmp = v0;
      *(uint4*)(tmp + 8) = v1;
#pragma unroll
      for (int j = 0; j < 16; j++) vt_lds[(d0v + j) * 72 + sV] = tmp[j];
    }
    __syncthreads();  // drains vmcnt: K resident; vt visible

    // S^T = K * Q^T
    floatx4 st[4];
#pragma unroll
    for (int i = 0; i < 4; i++) st[i] = (floatx4){0.f, 0.f, 0.f, 0.f};
#pragma unroll
    for (int i = 0; i < 4; i++) {
      short8 kf0 = *(const short8*)(k_lds + kOff[i]);
      short8 kf1 = *(const short8*)(k_lds + (kOff[i] ^ 32));
      st[i] = __builtin_amdgcn_mfma_f32_16x16x32_bf16(kf0, qf0, st[i], 0, 0, 0);
      st[i] = __builtin_amdgcn_mfma_f32_16x16x32_bf16(kf1, qf1, st[i], 0, 0, 0);
    }

    // causal mask: only the diagonal tile has any masked element for this wave
    if (s0 + 63 > qbase + 15) {
      int mg = qbase + l15;
#pragma unroll
      for (int i = 0; i < 4; i++)
#pragma unroll
        for (int r = 0; r < 4; r++) {
          int s = s0 + i * 16 + quad * 4 + r;
          if (s > mg) st[i][r] = -3.0e38f;
        }
    }

    // online softmax: lane owns one q-row (m = l15); keys in-lane (16) x quads (4)
    float mx = st[0][0];
#pragma unroll
    for (int i = 0; i < 4; i++)
#pragma unroll
      for (int r = 0; r < 4; r++) mx = fmaxf(mx, st[i][r]);
    mx = fmaxf(mx, __shfl_xor(mx, 16));
    mx = fmaxf(mx, __shfl_xor(mx, 32));
    float mnew = fmaxf(m_i, mx);
    float alpha = __expf(m_i - mnew);
    float ts = 0.0f;
#pragma unroll
    for (int i = 0; i < 4; i++)
#pragma unroll
      for (int r = 0; r < 4; r++) {
        float p = __expf(st[i][r] - mnew);
        st[i][r] = p;
        ts += p;
      }
    ts += __shfl_xor(ts, 16);
    ts += __shfl_xor(ts, 32);
    l_i = l_i * alpha + ts;
    m_i = mnew;

    // rescale accO: its rows are m = quad*4+r -> fetch those rows' alpha
    float aR[4];
#pragma unroll
    for (int r = 0; r < 4; r++) aR[r] = __shfl(alpha, quad * 4 + r);
#pragma unroll
    for (int jf = 0; jf < 4; jf++)
#pragma unroll
      for (int r = 0; r < 4; r++) accO[jf][r] *= aR[r];

    // P^T (C-layout) -> p_lds[m][s] with packed b64 writes
#pragma unroll
    for (int i = 0; i < 4; i++) {
      unsigned int lo = (unsigned int)f2bf(st[i][0]) | ((unsigned int)f2bf(st[i][1]) << 16);
      unsigned int hi = (unsigned int)f2bf(st[i][2]) | ((unsigned int)f2bf(st[i][3]) << 16);
      uint2 pk = {lo, hi};
      *(uint2*)(p_lds[w] + l15 * 72 + i * 16 + quad * 4) = pk;
    }

    // PV: O[m][d] += P[m][s] * V^T[d][s]
    short8 pf0 = *(const short8*)(p_lds[w] + pRd);
    short8 pf1 = *(const short8*)(p_lds[w] + pRd + 32);
#pragma unroll
    for (int jf = 0; jf < 4; jf++) {
      short8 vf0 = *(const short8*)(vt_lds + vOff[jf]);
      short8 vf1 = *(const short8*)(vt_lds + vOff[jf] + 32);
      accO[jf] = __builtin_amdgcn_mfma_f32_16x16x32_bf16(pf0, vf0, accO[jf], 0, 0, 0);
      accO[jf] = __builtin_amdgcn_mfma_f32_16x16x32_bf16(pf1, vf1, accO[jf], 0, 0, 0);
    }
  }

  // epilogue: accO rows m = quad*4+r, cols d = jf*16+l15; 1/l per row via shuffle
  float invl = 1.0f / l_i;
  float iR[4];
#pragma unroll
  for (int r = 0; r < 4; r++) iR[r] = __shfl(invl, quad * 4 + r);
  int orow = b * TT + qbase + quad * 4;
#pragma unroll
  for (int r = 0; r < 4; r++) {
    u16* op = attn + (size_t)(orow + r) * CC + h * 64 + l15;
#pragma unroll
    for (int jf = 0; jf < 4; jf++) op[jf * 16] = f2bf(accO[jf][r] * iR[r]);
  }
}

// ---------------- launch ----------------
extern "C" void kernel_launch(void* const* d_in, const int* in_sizes, int n_in,
                              void* d_out, int out_size, void* d_ws, size_t ws_size,
                              hipStream_t stream) {
  const float* x      = (const float*)d_in[0];
  const float* qkv_w  = (const float*)d_in[1];
  const float* proj_w = (const float*)d_in[2];
  const float* proj_b = (const float*)d_in[3];
  const float* l1_w   = (const float*)d_in[4];
  const float* l1_b   = (const float*)d_in[5];
  const float* l3_w   = (const float*)d_in[6];
  const float* l3_b   = (const float*)d_in[7];
  const float* ln1_g  = (const float*)d_in[8];
  const float* ln1_b  = (const float*)d_in[9];
  const float* ln2_g  = (const float*)d_in[10];
  const float* ln2_b  = (const float*)d_in[11];
  float* out = (float*)d_out;
  char* ws = (char*)d_ws;

  u16* w_qkv  = (u16*)(ws + 0);
  u16* w_proj = (u16*)(ws + 6291456);
  u16* w_l1   = (u16*)(ws + 8388608);
  u16* w_l3   = (u16*)(ws + 16777216);
  u16* lnb    = (u16*)(ws + 25165824);
  u16* qkvb   = (u16*)(ws + 33554432);
  u16* attnb  = (u16*)(ws + 58720256);
  float* x1   = (float*)(ws + 67108864);
  u16* hb     = (u16*)(ws + 83886080);

  cvt_bf16_kernel<<<3072, 256, 0, stream>>>(qkv_w, w_qkv);
  cvt_bf16_kernel<<<1024, 256, 0, stream>>>(proj_w, w_proj);
  cvt_bf16_kernel<<<4096, 256, 0, stream>>>(l1_w, w_l1);
  cvt_bf16_kernel<<<4096, 256, 0, stream>>>(l3_w, w_l3);

  ln_kernel<<<4096, 256, 0, stream>>>(x, ln1_g, ln1_b, lnb);
  gemm_bt<0><<<dim3(32, 24), 256, 0, stream>>>(lnb, w_qkv, nullptr, nullptr, nullptr,
                                               qkvb, 4096, 3072, 1024);
  flash_kernel<<<1024, 256, 0, stream>>>(qkvb, attnb);
  gemm_bt<1><<<dim3(32, 8), 256, 0, stream>>>(attnb, w_proj, proj_b, x, x1, nullptr,
                                              4096, 1024, 1024);
  ln_kernel<<<4096, 256, 0, stream>>>(x1, ln2_g, ln2_b, lnb);
  gemm_bt<2><<<dim3(32, 32), 256, 0, stream>>>(lnb, w_l1, l1_b, nullptr, nullptr, hb,
                                               4096, 4096, 1024);
  gemm_bt<1><<<dim3(32, 8), 256, 0, stream>>>(hb, w_l3, l3_b, x1, out, nullptr,
                                              4096, 1024, 4096);
}

// Round 3
// 350.176 us; speedup vs baseline: 1.6305x; 1.0502x over previous
//
#include <hip/hip_runtime.h>

typedef unsigned short u16;
typedef short short8 __attribute__((ext_vector_type(8)));
typedef float floatx4 __attribute__((ext_vector_type(4)));

#define TT 2048
#define CC 1024

__device__ __forceinline__ u16 f2bf(float f) {
  unsigned int u = __float_as_uint(f);
  u += 0x7fffu + ((u >> 16) & 1u);
  return (u16)(u >> 16);
}

__device__ __forceinline__ void glds16(const u16* g, u16* l) {
  __builtin_amdgcn_global_load_lds((const __attribute__((address_space(1))) void*)g,
                                   (__attribute__((address_space(3))) void*)l, 16, 0, 0);
}

// ---------------- fp32 -> bf16 convert (all 4 weights, one launch) ----------------
__global__ __launch_bounds__(256) void cvt_all_kernel(const float* __restrict__ w0,
                                                      const float* __restrict__ w1,
                                                      const float* __restrict__ w2,
                                                      const float* __restrict__ w3,
                                                      u16* __restrict__ o0,
                                                      u16* __restrict__ o1,
                                                      u16* __restrict__ o2,
                                                      u16* __restrict__ o3) {
  int blk = blockIdx.x;
  const float* in;
  u16* out;
  int base;
  if (blk < 3072)      { in = w0; out = o0; base = 0; }
  else if (blk < 4096) { in = w1; out = o1; base = 3072; }
  else if (blk < 8192) { in = w2; out = o2; base = 4096; }
  else                 { in = w3; out = o3; base = 8192; }
  int i = (blk - base) * 256 + threadIdx.x;
  float4 v = ((const float4*)in)[i];
  ushort4 o;
  o.x = f2bf(v.x); o.y = f2bf(v.y); o.z = f2bf(v.z); o.w = f2bf(v.w);
  ((ushort4*)out)[i] = o;
}

// ---------------- LayerNorm (unbiased std, /(std+eps)) -> bf16 ----------------
__global__ __launch_bounds__(256) void ln_kernel(const float* __restrict__ x,
                                                 const float* __restrict__ g,
                                                 const float* __restrict__ b,
                                                 u16* __restrict__ out) {
  int row = blockIdx.x;
  int tid = threadIdx.x;
  const float4* xr = (const float4*)(x + (size_t)row * CC);
  float4 v = xr[tid];
  float s = v.x + v.y + v.z + v.w;
  float sq = v.x * v.x + v.y * v.y + v.z * v.z + v.w * v.w;
#pragma unroll
  for (int off = 1; off < 64; off <<= 1) {
    s += __shfl_xor(s, off);
    sq += __shfl_xor(sq, off);
  }
  __shared__ float ss[4], ssq[4];
  int wave = tid >> 6;
  if ((tid & 63) == 0) { ss[wave] = s; ssq[wave] = sq; }
  __syncthreads();
  s = ss[0] + ss[1] + ss[2] + ss[3];
  sq = ssq[0] + ssq[1] + ssq[2] + ssq[3];
  float mean = s * (1.0f / CC);
  float var = (sq - (float)CC * mean * mean) * (1.0f / (CC - 1));
  float inv = 1.0f / (sqrtf(fmaxf(var, 0.0f)) + 1e-6f);
  float4 gv = ((const float4*)g)[tid];
  float4 bv = ((const float4*)b)[tid];
  ushort4 o;
  o.x = f2bf(gv.x * (v.x - mean) * inv + bv.x);
  o.y = f2bf(gv.y * (v.y - mean) * inv + bv.y);
  o.z = f2bf(gv.z * (v.z - mean) * inv + bv.z);
  o.w = f2bf(gv.w * (v.w - mean) * inv + bv.w);
  ((ushort4*)(out + (size_t)row * CC))[tid] = o;
}

// ---------------- GEMM (m97-style): out[m,n] = sum_k A[m,k] * W[n,k] ----------------
// Tile BM x 128, BK=64, global_load_lds width-16 staging, XOR-swizzled unpadded LDS.
// BM=128: wave-tile 64x64 (4x4 acc). BM=64: wave-tile 32x64 (2x4 acc) -> 2x blocks
// for small-N GEMMs (N=1024 at BM=128 gives only 256 blocks = 1 block/CU, latency-bound).
// MODE 0: qkv epilogue -> bf16 out, scale cols<1024 by 0.125 (q pre-scale), no bias
// MODE 1: + bias + fp32 residual -> fp32 out
// MODE 2: + bias, relu -> bf16 out
template <int BM, int MODE>
__global__ __launch_bounds__(256) void gemm_bt(const u16* __restrict__ A,
                                               const u16* __restrict__ W,
                                               const float* __restrict__ bias,
                                               const float* __restrict__ resid,
                                               float* __restrict__ outf,
                                               u16* __restrict__ outb,
                                               int M, int N, int K) {
  constexpr int MI = BM / 32;          // acc rows per wave: 4 (BM=128) or 2 (BM=64)
  __shared__ u16 a_lds[BM * 64];
  __shared__ u16 b_lds[128 * 64];
  int tid = threadIdx.x;
  int w = tid >> 6, lane = tid & 63;
  int l15 = lane & 15, quad = lane >> 4;
  int wm = (w >> 1) * (MI * 16), wn = (w & 1) * 64;
  int tm = blockIdx.x * BM, tn = blockIdx.y * 128;
  floatx4 acc[MI][4];
#pragma unroll
  for (int i = 0; i < MI; i++)
#pragma unroll
    for (int j = 0; j < 4; j++) acc[i][j] = (floatx4){0.f, 0.f, 0.f, 0.f};

  // staging: wave w covers BM/4 rows (A) / 32 rows (B); 8 rows per glds16 issue
  int rsub = lane >> 3;              // 0..7
  int cg = (lane & 7) ^ rsub;        // global 16B-chunk index (swizzled)
  const u16* Ag = A + (size_t)(tm + w * (BM / 4) + rsub) * K + cg * 8;
  const u16* Bg = W + (size_t)(tn + w * 32 + rsub) * K + cg * 8;
  u16* aL = a_lds + w * (BM / 4) * 64;
  u16* bL = b_lds + w * 32 * 64;

  // fragment read offsets (u16 units); LDS[r][cl] holds G[r][cl ^ (r&7)]
  int x = l15 & 7;
  int offA[MI], offB[4];
#pragma unroll
  for (int i = 0; i < MI; i++) offA[i] = (wm + i * 16 + l15) * 64 + ((quad ^ x) * 8);
#pragma unroll
  for (int j = 0; j < 4; j++) offB[j] = (wn + j * 16 + l15) * 64 + ((quad ^ x) * 8);

  for (int k0 = 0; k0 < K; k0 += 64) {
    __syncthreads();  // prior iter's readers done before overwrite
#pragma unroll
    for (int is = 0; is < BM / 32; is++) glds16(Ag + k0 + is * 8 * K, aL + is * 512);
#pragma unroll
    for (int is = 0; is < 4; is++) glds16(Bg + k0 + is * 8 * K, bL + is * 512);
    __syncthreads();  // drains vmcnt -> tiles resident
#pragma unroll
    for (int s = 0; s < 2; s++) {
      short8 af[MI], bw[4];
#pragma unroll
      for (int i = 0; i < MI; i++) af[i] = *(const short8*)(a_lds + (offA[i] ^ (s << 5)));
#pragma unroll
      for (int j = 0; j < 4; j++) bw[j] = *(const short8*)(b_lds + (offB[j] ^ (s << 5)));
#pragma unroll
      for (int i = 0; i < MI; i++)
#pragma unroll
        for (int j = 0; j < 4; j++)
          acc[i][j] = __builtin_amdgcn_mfma_f32_16x16x32_bf16(af[i], bw[j], acc[i][j], 0, 0, 0);
    }
  }

#pragma unroll
  for (int i = 0; i < MI; i++) {
    int row0 = tm + wm + i * 16 + quad * 4;
#pragma unroll
    for (int j = 0; j < 4; j++) {
      int col = tn + wn + j * 16 + l15;
      float bb = (MODE != 0) ? bias[col] : 0.0f;
#pragma unroll
      for (int r = 0; r < 4; r++) {
        int row = row0 + r;
        float v = acc[i][j][r];
        if (MODE == 0) {
          if (col < 1024) v *= 0.125f;
          outb[(size_t)row * N + col] = f2bf(v);
        } else if (MODE == 1) {
          outf[(size_t)row * N + col] = v + bb + resid[(size_t)row * N + col];
        } else {
          outb[(size_t)row * N + col] = f2bf(fmaxf(v + bb, 0.0f));
        }
      }
    }
  }
}

// ---------------- Flash attention (causal), S^T formulation ----------------
// qkv: [b*T + t][3072] bf16; q (pre-scaled 0.125) cols [0,1024), k [1024,2048), v [2048,3072).
// Block = 64 q-rows x (b,h); 4 waves x 16 q-rows; KV tile = 64 keys.
// S^T = mfma(A=K-frag, B=Q-frag): lane l15 = q-row m, quad*4+r (+16i) = key s.
__global__ __launch_bounds__(256) void flash_kernel(const u16* __restrict__ qkv,
                                                    u16* __restrict__ attn) {
  int bid = blockIdx.x;
  int qt = 31 - (bid >> 5);   // long blocks first
  int bh = bid & 31;
  int b = bh >> 4, h = bh & 15;
  int tid = threadIdx.x, w = tid >> 6, lane = tid & 63;
  int l15 = lane & 15, quad = lane >> 4;

  __shared__ u16 k_lds[64 * 64];        // chunk-swizzled, unpadded (global_load_lds)
  __shared__ u16 vt_lds[64 * 72];       // V^T: [d][s], stride 72
  __shared__ u16 p_lds[4][16 * 72];     // per-wave P: [m][s], stride 72

  int qbase = qt * 64 + w * 16;
  const u16* qp = qkv + (size_t)(b * TT + qbase + l15) * 3072 + h * 64;
  short8 qf0 = *(const short8*)(qp + quad * 8);
  short8 qf1 = *(const short8*)(qp + 32 + quad * 8);

  float m_i = -3.0e38f, l_i = 0.0f;
  floatx4 accO[4];
#pragma unroll
  for (int jf = 0; jf < 4; jf++) accO[jf] = (floatx4){0.f, 0.f, 0.f, 0.f};

  // K staging (global_load_lds): wave w rows [w*16, w*16+16), 2 issues of 8 rows
  int rsub = lane >> 3;
  int cg = (lane & 7) ^ rsub;
  const u16* Kg = qkv + (size_t)(b * TT + w * 16 + rsub) * 3072 + 1024 + h * 64 + cg * 8;
  u16* kL = k_lds + w * 16 * 64;
  // V staging with transpose: thread -> (s = tid&63, d0 = (tid>>6)*16)
  int sV = tid & 63, d0v = (tid >> 6) * 16;
  const u16* Vg = qkv + (size_t)(b * TT + sV) * 3072 + 2048 + h * 64 + d0v;

  int x = l15 & 7;
  int kOff[4], vOff[4];
#pragma unroll
  for (int i = 0; i < 4; i++) kOff[i] = (i * 16 + l15) * 64 + ((quad ^ x) * 8);
#pragma unroll
  for (int jf = 0; jf < 4; jf++) vOff[jf] = (jf * 16 + l15) * 72 + quad * 8;
  int pRd = l15 * 72 + quad * 8;

  int kt_end = qt + 1;
  for (int kt = 0; kt < kt_end; kt++) {
    int s0 = kt * 64;
    size_t soff = (size_t)s0 * 3072;
    uint4 v0 = *(const uint4*)(Vg + soff);
    uint4 v1 = *(const uint4*)(Vg + soff + 8);
    __syncthreads();  // prior tile's readers done
#pragma unroll
    for (int is = 0; is < 2; is++) glds16(Kg + soff + (size_t)is * 8 * 3072, kL + is * 512);
    {
      u16 tmp[16];
      *(uint4*)tmp = v0;
      *(uint4*)(tmp + 8) = v1;
#pragma unroll
      for (int j = 0; j < 16; j++) vt_lds[(d0v + j) * 72 + sV] = tmp[j];
    }
    __syncthreads();  // drains vmcnt: K resident; vt visible

    // S^T = K * Q^T
    floatx4 st[4];
#pragma unroll
    for (int i = 0; i < 4; i++) st[i] = (floatx4){0.f, 0.f, 0.f, 0.f};
#pragma unroll
    for (int i = 0; i < 4; i++) {
      short8 kf0 = *(const short8*)(k_lds + kOff[i]);
      short8 kf1 = *(const short8*)(k_lds + (kOff[i] ^ 32));
      st[i] = __builtin_amdgcn_mfma_f32_16x16x32_bf16(kf0, qf0, st[i], 0, 0, 0);
      st[i] = __builtin_amdgcn_mfma_f32_16x16x32_bf16(kf1, qf1, st[i], 0, 0, 0);
    }

    // causal mask: only the diagonal tile has any masked element for this wave
    if (s0 + 63 > qbase + 15) {
      int mg = qbase + l15;
#pragma unroll
      for (int i = 0; i < 4; i++)
#pragma unroll
        for (int r = 0; r < 4; r++) {
          int s = s0 + i * 16 + quad * 4 + r;
          if (s > mg) st[i][r] = -3.0e38f;
        }
    }

    // online softmax: lane owns one q-row (m = l15); keys in-lane (16) x quads (4)
    float mx = st[0][0];
#pragma unroll
    for (int i = 0; i < 4; i++)
#pragma unroll
      for (int r = 0; r < 4; r++) mx = fmaxf(mx, st[i][r]);
    mx = fmaxf(mx, __shfl_xor(mx, 16));
    mx = fmaxf(mx, __shfl_xor(mx, 32));
    float mnew = fmaxf(m_i, mx);
    float alpha = __expf(m_i - mnew);
    float ts = 0.0f;
#pragma unroll
    for (int i = 0; i < 4; i++)
#pragma unroll
      for (int r = 0; r < 4; r++) {
        float p = __expf(st[i][r] - mnew);
        st[i][r] = p;
        ts += p;
      }
    ts += __shfl_xor(ts, 16);
    ts += __shfl_xor(ts, 32);
    l_i = l_i * alpha + ts;
    m_i = mnew;

    // rescale accO: its rows are m = quad*4+r -> fetch those rows' alpha
    float aR[4];
#pragma unroll
    for (int r = 0; r < 4; r++) aR[r] = __shfl(alpha, quad * 4 + r);
#pragma unroll
    for (int jf = 0; jf < 4; jf++)
#pragma unroll
      for (int r = 0; r < 4; r++) accO[jf][r] *= aR[r];

    // P^T (C-layout) -> p_lds[m][s] with packed b64 writes
#pragma unroll
    for (int i = 0; i < 4; i++) {
      unsigned int lo = (unsigned int)f2bf(st[i][0]) | ((unsigned int)f2bf(st[i][1]) << 16);
      unsigned int hi = (unsigned int)f2bf(st[i][2]) | ((unsigned int)f2bf(st[i][3]) << 16);
      uint2 pk = {lo, hi};
      *(uint2*)(p_lds[w] + l15 * 72 + i * 16 + quad * 4) = pk;
    }

    // PV: O[m][d] += P[m][s] * V^T[d][s]
    short8 pf0 = *(const short8*)(p_lds[w] + pRd);
    short8 pf1 = *(const short8*)(p_lds[w] + pRd + 32);
#pragma unroll
    for (int jf = 0; jf < 4; jf++) {
      short8 vf0 = *(const short8*)(vt_lds + vOff[jf]);
      short8 vf1 = *(const short8*)(vt_lds + vOff[jf] + 32);
      accO[jf] = __builtin_amdgcn_mfma_f32_16x16x32_bf16(pf0, vf0, accO[jf], 0, 0, 0);
      accO[jf] = __builtin_amdgcn_mfma_f32_16x16x32_bf16(pf1, vf1, accO[jf], 0, 0, 0);
    }
  }

  // epilogue: accO rows m = quad*4+r, cols d = jf*16+l15; 1/l per row via shuffle
  float invl = 1.0f / l_i;
  float iR[4];
#pragma unroll
  for (int r = 0; r < 4; r++) iR[r] = __shfl(invl, quad * 4 + r);
  int orow = b * TT + qbase + quad * 4;
#pragma unroll
  for (int r = 0; r < 4; r++) {
    u16* op = attn + (size_t)(orow + r) * CC + h * 64 + l15;
#pragma unroll
    for (int jf = 0; jf < 4; jf++) op[jf * 16] = f2bf(accO[jf][r] * iR[r]);
  }
}

// ---------------- launch ----------------
extern "C" void kernel_launch(void* const* d_in, const int* in_sizes, int n_in,
                              void* d_out, int out_size, void* d_ws, size_t ws_size,
                              hipStream_t stream) {
  const float* x      = (const float*)d_in[0];
  const float* qkv_w  = (const float*)d_in[1];
  const float* proj_w = (const float*)d_in[2];
  const float* proj_b = (const float*)d_in[3];
  const float* l1_w   = (const float*)d_in[4];
  const float* l1_b   = (const float*)d_in[5];
  const float* l3_w   = (const float*)d_in[6];
  const float* l3_b   = (const float*)d_in[7];
  const float* ln1_g  = (const float*)d_in[8];
  const float* ln1_b  = (const float*)d_in[9];
  const float* ln2_g  = (const float*)d_in[10];
  const float* ln2_b  = (const float*)d_in[11];
  float* out = (float*)d_out;
  char* ws = (char*)d_ws;

  u16* w_qkv  = (u16*)(ws + 0);
  u16* w_proj = (u16*)(ws + 6291456);
  u16* w_l1   = (u16*)(ws + 8388608);
  u16* w_l3   = (u16*)(ws + 16777216);
  u16* lnb    = (u16*)(ws + 25165824);
  u16* qkvb   = (u16*)(ws + 33554432);
  u16* attnb  = (u16*)(ws + 58720256);
  float* x1   = (float*)(ws + 67108864);
  u16* hb     = (u16*)(ws + 83886080);

  cvt_all_kernel<<<12288, 256, 0, stream>>>(qkv_w, proj_w, l1_w, l3_w,
                                            w_qkv, w_proj, w_l1, w_l3);

  ln_kernel<<<4096, 256, 0, stream>>>(x, ln1_g, ln1_b, lnb);
  gemm_bt<128, 0><<<dim3(32, 24), 256, 0, stream>>>(lnb, w_qkv, nullptr, nullptr, nullptr,
                                                    qkvb, 4096, 3072, 1024);
  flash_kernel<<<1024, 256, 0, stream>>>(qkvb, attnb);
  gemm_bt<64, 1><<<dim3(64, 8), 256, 0, stream>>>(attnb, w_proj, proj_b, x, x1, nullptr,
                                                  4096, 1024, 1024);
  ln_kernel<<<4096, 256, 0, stream>>>(x1, ln2_g, ln2_b, lnb);
  gemm_bt<128, 2><<<dim3(32, 32), 256, 0, stream>>>(lnb, w_l1, l1_b, nullptr, nullptr, hb,
                                                    4096, 4096, 1024);
  gemm_bt<64, 1><<<dim3(64, 8), 256, 0, stream>>>(hb, w_l3, l3_b, x1, out, nullptr,
                                                  4096, 1024, 4096);
}

// Round 4
// 328.785 us; speedup vs baseline: 1.7366x; 1.0651x over previous
//
#include <hip/hip_runtime.h>

typedef unsigned short u16;
typedef short short8 __attribute__((ext_vector_type(8)));
typedef float floatx4 __attribute__((ext_vector_type(4)));

#define TT 2048
#define CC 1024

__device__ __forceinline__ u16 f2bf(float f) {
  unsigned int u = __float_as_uint(f);
  u += 0x7fffu + ((u >> 16) & 1u);
  return (u16)(u >> 16);
}

__device__ __forceinline__ void glds16(const u16* g, u16* l) {
  __builtin_amdgcn_global_load_lds((const __attribute__((address_space(1))) void*)g,
                                   (__attribute__((address_space(3))) void*)l, 16, 0, 0);
}

// ---------------- fp32 -> bf16 convert (all 4 weights, one launch) ----------------
__global__ __launch_bounds__(256) void cvt_all_kernel(const float* __restrict__ w0,
                                                      const float* __restrict__ w1,
                                                      const float* __restrict__ w2,
                                                      const float* __restrict__ w3,
                                                      u16* __restrict__ o0,
                                                      u16* __restrict__ o1,
                                                      u16* __restrict__ o2,
                                                      u16* __restrict__ o3) {
  int blk = blockIdx.x;
  const float* in;
  u16* out;
  int base;
  if (blk < 3072)      { in = w0; out = o0; base = 0; }
  else if (blk < 4096) { in = w1; out = o1; base = 3072; }
  else if (blk < 8192) { in = w2; out = o2; base = 4096; }
  else                 { in = w3; out = o3; base = 8192; }
  int i = (blk - base) * 256 + threadIdx.x;
  float4 v = ((const float4*)in)[i];
  ushort4 o;
  o.x = f2bf(v.x); o.y = f2bf(v.y); o.z = f2bf(v.z); o.w = f2bf(v.w);
  ((ushort4*)out)[i] = o;
}

// ---------------- LayerNorm (unbiased std, /(std+eps)) -> bf16 ----------------
__global__ __launch_bounds__(256) void ln_kernel(const float* __restrict__ x,
                                                 const float* __restrict__ g,
                                                 const float* __restrict__ b,
                                                 u16* __restrict__ out) {
  int row = blockIdx.x;
  int tid = threadIdx.x;
  const float4* xr = (const float4*)(x + (size_t)row * CC);
  float4 v = xr[tid];
  float s = v.x + v.y + v.z + v.w;
  float sq = v.x * v.x + v.y * v.y + v.z * v.z + v.w * v.w;
#pragma unroll
  for (int off = 1; off < 64; off <<= 1) {
    s += __shfl_xor(s, off);
    sq += __shfl_xor(sq, off);
  }
  __shared__ float ss[4], ssq[4];
  int wave = tid >> 6;
  if ((tid & 63) == 0) { ss[wave] = s; ssq[wave] = sq; }
  __syncthreads();
  s = ss[0] + ss[1] + ss[2] + ss[3];
  sq = ssq[0] + ssq[1] + ssq[2] + ssq[3];
  float mean = s * (1.0f / CC);
  float var = (sq - (float)CC * mean * mean) * (1.0f / (CC - 1));
  float inv = 1.0f / (sqrtf(fmaxf(var, 0.0f)) + 1e-6f);
  float4 gv = ((const float4*)g)[tid];
  float4 bv = ((const float4*)b)[tid];
  ushort4 o;
  o.x = f2bf(gv.x * (v.x - mean) * inv + bv.x);
  o.y = f2bf(gv.y * (v.y - mean) * inv + bv.y);
  o.z = f2bf(gv.z * (v.z - mean) * inv + bv.z);
  o.w = f2bf(gv.w * (v.w - mean) * inv + bv.w);
  ((ushort4*)(out + (size_t)row * CC))[tid] = o;
}

// ---------------- GEMM (m97-style): out[m,n] = sum_k A[m,k] * W[n,k] ----------------
// Tile BM x 128, BK=64, global_load_lds width-16 staging, XOR-swizzled unpadded LDS.
// lda = row stride of A and W (elements); K = iteration extent; blockIdx.z (split-K)
// offsets the k-range by z*K and (MODE 3) the output by z*M*N.
// MODE 0: qkv epilogue -> bf16 out, scale cols<1024 by 0.125 (q pre-scale), no bias
// MODE 1: + bias + fp32 residual -> fp32 out
// MODE 2: + bias, relu -> bf16 out
// MODE 3: raw fp32 partial -> outf + z*M*N (split-K)
template <int BM, int MODE>
__global__ __launch_bounds__(256) void gemm_bt(const u16* __restrict__ A,
                                               const u16* __restrict__ W,
                                               const float* __restrict__ bias,
                                               const float* __restrict__ resid,
                                               float* __restrict__ outf,
                                               u16* __restrict__ outb,
                                               int M, int N, int K, int lda) {
  constexpr int MI = BM / 32;          // acc rows per wave: 4 (BM=128) or 2 (BM=64)
  __shared__ u16 a_lds[BM * 64];
  __shared__ u16 b_lds[128 * 64];
  int tid = threadIdx.x;
  int w = tid >> 6, lane = tid & 63;
  int l15 = lane & 15, quad = lane >> 4;
  int wm = (w >> 1) * (MI * 16), wn = (w & 1) * 64;
  int tm = blockIdx.x * BM, tn = blockIdx.y * 128;
  size_t koff = (size_t)blockIdx.z * K;
  floatx4 acc[MI][4];
#pragma unroll
  for (int i = 0; i < MI; i++)
#pragma unroll
    for (int j = 0; j < 4; j++) acc[i][j] = (floatx4){0.f, 0.f, 0.f, 0.f};

  // staging: wave w covers BM/4 rows (A) / 32 rows (B); 8 rows per glds16 issue
  int rsub = lane >> 3;              // 0..7
  int cg = (lane & 7) ^ rsub;        // global 16B-chunk index (swizzled)
  const u16* Ag = A + (size_t)(tm + w * (BM / 4) + rsub) * lda + koff + cg * 8;
  const u16* Bg = W + (size_t)(tn + w * 32 + rsub) * lda + koff + cg * 8;
  u16* aL = a_lds + w * (BM / 4) * 64;
  u16* bL = b_lds + w * 32 * 64;

  // fragment read offsets (u16 units); LDS[r][cl] holds G[r][cl ^ (r&7)]
  int x = l15 & 7;
  int offA[MI], offB[4];
#pragma unroll
  for (int i = 0; i < MI; i++) offA[i] = (wm + i * 16 + l15) * 64 + ((quad ^ x) * 8);
#pragma unroll
  for (int j = 0; j < 4; j++) offB[j] = (wn + j * 16 + l15) * 64 + ((quad ^ x) * 8);

  for (int k0 = 0; k0 < K; k0 += 64) {
    __syncthreads();  // prior iter's readers done before overwrite
#pragma unroll
    for (int is = 0; is < BM / 32; is++) glds16(Ag + k0 + (size_t)is * 8 * lda, aL + is * 512);
#pragma unroll
    for (int is = 0; is < 4; is++) glds16(Bg + k0 + (size_t)is * 8 * lda, bL + is * 512);
    __syncthreads();  // drains vmcnt -> tiles resident
#pragma unroll
    for (int s = 0; s < 2; s++) {
      short8 af[MI], bw[4];
#pragma unroll
      for (int i = 0; i < MI; i++) af[i] = *(const short8*)(a_lds + (offA[i] ^ (s << 5)));
#pragma unroll
      for (int j = 0; j < 4; j++) bw[j] = *(const short8*)(b_lds + (offB[j] ^ (s << 5)));
#pragma unroll
      for (int i = 0; i < MI; i++)
#pragma unroll
        for (int j = 0; j < 4; j++)
          acc[i][j] = __builtin_amdgcn_mfma_f32_16x16x32_bf16(af[i], bw[j], acc[i][j], 0, 0, 0);
    }
  }

  float* po = (MODE == 3) ? outf + (size_t)blockIdx.z * M * N : outf;
#pragma unroll
  for (int i = 0; i < MI; i++) {
    int row0 = tm + wm + i * 16 + quad * 4;
#pragma unroll
    for (int j = 0; j < 4; j++) {
      int col = tn + wn + j * 16 + l15;
      float bb = (MODE == 1 || MODE == 2) ? bias[col] : 0.0f;
#pragma unroll
      for (int r = 0; r < 4; r++) {
        int row = row0 + r;
        float v = acc[i][j][r];
        if (MODE == 0) {
          if (col < 1024) v *= 0.125f;
          outb[(size_t)row * N + col] = f2bf(v);
        } else if (MODE == 1) {
          outf[(size_t)row * N + col] = v + bb + resid[(size_t)row * N + col];
        } else if (MODE == 2) {
          outb[(size_t)row * N + col] = f2bf(fmaxf(v + bb, 0.0f));
        } else {
          po[(size_t)row * N + col] = v;
        }
      }
    }
  }
}

// ---------------- split-K reduce: out = p0 + p1 + bias + resid (fp32) ----------------
__global__ __launch_bounds__(256) void reduce2_kernel(const float* __restrict__ p,
                                                      const float* __restrict__ bias,
                                                      const float* __restrict__ resid,
                                                      float* __restrict__ out) {
  int i = blockIdx.x * 256 + threadIdx.x;           // float4 index, 4096*256 = 1M
  float4 a = ((const float4*)p)[i];
  float4 b = ((const float4*)p)[i + 1048576];
  float4 r = ((const float4*)resid)[i];
  float4 bb = ((const float4*)bias)[i & 255];
  float4 o;
  o.x = a.x + b.x + r.x + bb.x;
  o.y = a.y + b.y + r.y + bb.y;
  o.z = a.z + b.z + r.z + bb.z;
  o.w = a.w + b.w + r.w + bb.w;
  ((float4*)out)[i] = o;
}

// ---------------- Flash attention (causal), S^T formulation, 128-key tiles -------
// qkv: [b*T + t][3072] bf16; q (pre-scaled 0.125) cols [0,1024), k [1024,2048), v [2048,3072).
// Block = 64 q-rows x (b,h); 4 waves x 16 q-rows; KV tile = 128 keys.
// S^T = mfma(A=K-frag, B=Q-frag): lane l15 = q-row m, i*16 + quad*4+r = key s.
__global__ __launch_bounds__(256) void flash_kernel(const u16* __restrict__ qkv,
                                                    u16* __restrict__ attn) {
  int bid = blockIdx.x;
  int qt = 31 - (bid >> 5);   // long blocks first
  int bh = bid & 31;
  int b = bh >> 4, h = bh & 15;
  int tid = threadIdx.x, w = tid >> 6, lane = tid & 63;
  int l15 = lane & 15, quad = lane >> 4;

  __shared__ u16 k_lds[128 * 64];       // chunk-swizzled, unpadded (global_load_lds)
  __shared__ u16 vt_lds[64 * 136];      // V^T: [d][s], stride 136 (128 + 8 pad)
  __shared__ u16 p_lds[4][16 * 136];    // per-wave P: [m][s], stride 136

  int qbase = qt * 64 + w * 16;
  const u16* qp = qkv + (size_t)(b * TT + qbase + l15) * 3072 + h * 64;
  short8 qf0 = *(const short8*)(qp + quad * 8);
  short8 qf1 = *(const short8*)(qp + 32 + quad * 8);

  float m_i = -3.0e38f, l_i = 0.0f;
  floatx4 accO[4];
#pragma unroll
  for (int jf = 0; jf < 4; jf++) accO[jf] = (floatx4){0.f, 0.f, 0.f, 0.f};

  // K staging (global_load_lds): wave w rows [w*32, w*32+32), 4 issues of 8 rows
  int rsub = lane >> 3;
  int cg = (lane & 7) ^ rsub;
  const u16* Kg = qkv + (size_t)(b * TT + w * 32 + rsub) * 3072 + 1024 + h * 64 + cg * 8;
  u16* kL = k_lds + w * 32 * 64;
  // V staging with transpose: thread -> (s = tid&127, d-half = (tid>>7)*32)
  int sV = tid & 127, d0v = (tid >> 7) * 32;
  const u16* Vg = qkv + (size_t)(b * TT + sV) * 3072 + 2048 + h * 64 + d0v;

  int x = l15 & 7;
  int kOff[8];
#pragma unroll
  for (int i = 0; i < 8; i++) kOff[i] = (i * 16 + l15) * 64 + ((quad ^ x) * 8);
  int pRd = l15 * 136 + quad * 8;

  int nt = (qt + 2) >> 1;               // ceil((qt+1)*64 / 128)
  for (int kt = 0; kt < nt; kt++) {
    int s0 = kt * 128;
    size_t soff = (size_t)s0 * 3072;
    uint4 v0 = *(const uint4*)(Vg + soff);
    uint4 v1 = *(const uint4*)(Vg + soff + 8);
    uint4 v2 = *(const uint4*)(Vg + soff + 16);
    uint4 v3 = *(const uint4*)(Vg + soff + 24);
    __syncthreads();  // prior tile's readers done
#pragma unroll
    for (int is = 0; is < 4; is++) glds16(Kg + soff + (size_t)is * 8 * 3072, kL + is * 512);
    {
      u16 tmp[32];
      *(uint4*)tmp = v0;
      *(uint4*)(tmp + 8) = v1;
      *(uint4*)(tmp + 16) = v2;
      *(uint4*)(tmp + 24) = v3;
#pragma unroll
      for (int j = 0; j < 32; j++) vt_lds[(d0v + j) * 136 + sV] = tmp[j];
    }
    __syncthreads();  // drains vmcnt: K resident; vt visible

    // S^T = K * Q^T  (8 key-subtiles of 16)
    floatx4 st[8];
#pragma unroll
    for (int i = 0; i < 8; i++) st[i] = (floatx4){0.f, 0.f, 0.f, 0.f};
#pragma unroll
    for (int i = 0; i < 8; i++) {
      short8 kf0 = *(const short8*)(k_lds + kOff[i]);
      short8 kf1 = *(const short8*)(k_lds + (kOff[i] ^ 32));
      st[i] = __builtin_amdgcn_mfma_f32_16x16x32_bf16(kf0, qf0, st[i], 0, 0, 0);
      st[i] = __builtin_amdgcn_mfma_f32_16x16x32_bf16(kf1, qf1, st[i], 0, 0, 0);
    }

    // causal mask (wave-uniform branch; only tiles overlapping the diagonal)
    if (s0 + 127 > qbase) {
      int mg = qbase + l15;
#pragma unroll
      for (int i = 0; i < 8; i++)
#pragma unroll
        for (int r = 0; r < 4; r++) {
          int s = s0 + i * 16 + quad * 4 + r;
          if (s > mg) st[i][r] = -3.0e38f;
        }
    }

    // online softmax: lane owns one q-row (m = l15); 32 keys in-lane x 4 quads
    float mx = st[0][0];
#pragma unroll
    for (int i = 0; i < 8; i++)
#pragma unroll
      for (int r = 0; r < 4; r++) mx = fmaxf(mx, st[i][r]);
    mx = fmaxf(mx, __shfl_xor(mx, 16));
    mx = fmaxf(mx, __shfl_xor(mx, 32));
    float mnew = fmaxf(m_i, mx);
    float alpha = __expf(m_i - mnew);
    float ts = 0.0f;
#pragma unroll
    for (int i = 0; i < 8; i++)
#pragma unroll
      for (int r = 0; r < 4; r++) {
        float p = __expf(st[i][r] - mnew);
        st[i][r] = p;
        ts += p;
      }
    ts += __shfl_xor(ts, 16);
    ts += __shfl_xor(ts, 32);
    l_i = l_i * alpha + ts;
    m_i = mnew;

    // rescale accO: its rows are m = quad*4+r -> fetch those rows' alpha
    float aR[4];
#pragma unroll
    for (int r = 0; r < 4; r++) aR[r] = __shfl(alpha, quad * 4 + r);
#pragma unroll
    for (int jf = 0; jf < 4; jf++)
#pragma unroll
      for (int r = 0; r < 4; r++) accO[jf][r] *= aR[r];

    // P^T (C-layout) -> p_lds[m][s] with packed b64 writes
#pragma unroll
    for (int i = 0; i < 8; i++) {
      unsigned int lo = (unsigned int)f2bf(st[i][0]) | ((unsigned int)f2bf(st[i][1]) << 16);
      unsigned int hi = (unsigned int)f2bf(st[i][2]) | ((unsigned int)f2bf(st[i][3]) << 16);
      uint2 pk = {lo, hi};
      *(uint2*)(p_lds[w] + l15 * 136 + i * 16 + quad * 4) = pk;
    }

    // PV: O[m][d] += P[m][s] * V^T[d][s], K-dim = 128 keys = 4 chunks of 32
    short8 pf[4];
#pragma unroll
    for (int c = 0; c < 4; c++) pf[c] = *(const short8*)(p_lds[w] + pRd + c * 32);
#pragma unroll
    for (int jf = 0; jf < 4; jf++) {
      int vOff = (jf * 16 + l15) * 136 + quad * 8;
#pragma unroll
      for (int c = 0; c < 4; c++) {
        short8 vf = *(const short8*)(vt_lds + vOff + c * 32);
        accO[jf] = __builtin_amdgcn_mfma_f32_16x16x32_bf16(pf[c], vf, accO[jf], 0, 0, 0);
      }
    }
  }

  // epilogue: accO rows m = quad*4+r, cols d = jf*16+l15; 1/l per row via shuffle
  float invl = 1.0f / l_i;
  float iR[4];
#pragma unroll
  for (int r = 0; r < 4; r++) iR[r] = __shfl(invl, quad * 4 + r);
  int orow = b * TT + qbase + quad * 4;
#pragma unroll
  for (int r = 0; r < 4; r++) {
    u16* op = attn + (size_t)(orow + r) * CC + h * 64 + l15;
#pragma unroll
    for (int jf = 0; jf < 4; jf++) op[jf * 16] = f2bf(accO[jf][r] * iR[r]);
  }
}

// ---------------- launch ----------------
extern "C" void kernel_launch(void* const* d_in, const int* in_sizes, int n_in,
                              void* d_out, int out_size, void* d_ws, size_t ws_size,
                              hipStream_t stream) {
  const float* x      = (const float*)d_in[0];
  const float* qkv_w  = (const float*)d_in[1];
  const float* proj_w = (const float*)d_in[2];
  const float* proj_b = (const float*)d_in[3];
  const float* l1_w   = (const float*)d_in[4];
  const float* l1_b   = (const float*)d_in[5];
  const float* l3_w   = (const float*)d_in[6];
  const float* l3_b   = (const float*)d_in[7];
  const float* ln1_g  = (const float*)d_in[8];
  const float* ln1_b  = (const float*)d_in[9];
  const float* ln2_g  = (const float*)d_in[10];
  const float* ln2_b  = (const float*)d_in[11];
  float* out = (float*)d_out;
  char* ws = (char*)d_ws;

  u16* w_qkv  = (u16*)(ws + 0);
  u16* w_proj = (u16*)(ws + 6291456);
  u16* w_l1   = (u16*)(ws + 8388608);
  u16* w_l3   = (u16*)(ws + 16777216);
  u16* lnb    = (u16*)(ws + 25165824);
  u16* qkvb   = (u16*)(ws + 33554432);
  u16* attnb  = (u16*)(ws + 58720256);
  float* x1   = (float*)(ws + 67108864);
  u16* hb     = (u16*)(ws + 83886080);
  // l3 split-K partials reuse dead qkvb+attnb region: [33554432, 67108864) = 2 x 16.8 MB
  float* l3p  = (float*)(ws + 33554432);

  cvt_all_kernel<<<12288, 256, 0, stream>>>(qkv_w, proj_w, l1_w, l3_w,
                                            w_qkv, w_proj, w_l1, w_l3);

  ln_kernel<<<4096, 256, 0, stream>>>(x, ln1_g, ln1_b, lnb);
  gemm_bt<128, 0><<<dim3(32, 24), 256, 0, stream>>>(lnb, w_qkv, nullptr, nullptr, nullptr,
                                                    qkvb, 4096, 3072, 1024, 1024);
  flash_kernel<<<1024, 256, 0, stream>>>(qkvb, attnb);
  gemm_bt<64, 1><<<dim3(64, 8), 256, 0, stream>>>(attnb, w_proj, proj_b, x, x1, nullptr,
                                                  4096, 1024, 1024, 1024);
  ln_kernel<<<4096, 256, 0, stream>>>(x1, ln2_g, ln2_b, lnb);
  gemm_bt<128, 2><<<dim3(32, 32), 256, 0, stream>>>(lnb, w_l1, l1_b, nullptr, nullptr, hb,
                                                    4096, 4096, 1024, 1024);
  // l3: split-K=2 over K=4096 (each z does K=2048), partials -> l3p, then fused reduce
  gemm_bt<64, 3><<<dim3(64, 8, 2), 256, 0, stream>>>(hb, w_l3, nullptr, nullptr, l3p,
                                                     nullptr, 4096, 1024, 2048, 4096);
  reduce2_kernel<<<4096, 256, 0, stream>>>(l3p, l3_b, x1, out);
}

// Round 5
// 322.341 us; speedup vs baseline: 1.7713x; 1.0200x over previous
//
#include <hip/hip_runtime.h>

typedef unsigned short u16;
typedef short short8 __attribute__((ext_vector_type(8)));
typedef float floatx4 __attribute__((ext_vector_type(4)));

#define TT 2048
#define CC 1024

__device__ __forceinline__ u16 f2bf(float f) {
  unsigned int u = __float_as_uint(f);
  u += 0x7fffu + ((u >> 16) & 1u);
  return (u16)(u >> 16);
}

// pack 2 floats -> bf16x2 (round-half-up; ±1ulp vs RNE, 4 VALU ops)
__device__ __forceinline__ unsigned int pk2bf(float a, float b) {
  unsigned int ua = __float_as_uint(a) + 0x8000u;
  unsigned int ub = __float_as_uint(b) + 0x8000u;
  return (ua >> 16) | (ub & 0xffff0000u);
}

__device__ __forceinline__ void glds16(const u16* g, u16* l) {
  __builtin_amdgcn_global_load_lds((const __attribute__((address_space(1))) void*)g,
                                   (__attribute__((address_space(3))) void*)l, 16, 0, 0);
}

// ---------------- fp32 -> bf16 convert (all 4 weights, one launch) ----------------
__global__ __launch_bounds__(256) void cvt_all_kernel(const float* __restrict__ w0,
                                                      const float* __restrict__ w1,
                                                      const float* __restrict__ w2,
                                                      const float* __restrict__ w3,
                                                      u16* __restrict__ o0,
                                                      u16* __restrict__ o1,
                                                      u16* __restrict__ o2,
                                                      u16* __restrict__ o3) {
  int blk = blockIdx.x;
  const float* in;
  u16* out;
  int base;
  if (blk < 3072)      { in = w0; out = o0; base = 0; }
  else if (blk < 4096) { in = w1; out = o1; base = 3072; }
  else if (blk < 8192) { in = w2; out = o2; base = 4096; }
  else                 { in = w3; out = o3; base = 8192; }
  int i = (blk - base) * 256 + threadIdx.x;
  float4 v = ((const float4*)in)[i];
  ushort4 o;
  o.x = f2bf(v.x); o.y = f2bf(v.y); o.z = f2bf(v.z); o.w = f2bf(v.w);
  ((ushort4*)out)[i] = o;
}

// ---------------- LayerNorm (unbiased std, /(std+eps)) -> bf16 ----------------
__global__ __launch_bounds__(256) void ln_kernel(const float* __restrict__ x,
                                                 const float* __restrict__ g,
                                                 const float* __restrict__ b,
                                                 u16* __restrict__ out) {
  int row = blockIdx.x;
  int tid = threadIdx.x;
  const float4* xr = (const float4*)(x + (size_t)row * CC);
  float4 v = xr[tid];
  float s = v.x + v.y + v.z + v.w;
  float sq = v.x * v.x + v.y * v.y + v.z * v.z + v.w * v.w;
#pragma unroll
  for (int off = 1; off < 64; off <<= 1) {
    s += __shfl_xor(s, off);
    sq += __shfl_xor(sq, off);
  }
  __shared__ float ss[4], ssq[4];
  int wave = tid >> 6;
  if ((tid & 63) == 0) { ss[wave] = s; ssq[wave] = sq; }
  __syncthreads();
  s = ss[0] + ss[1] + ss[2] + ss[3];
  sq = ssq[0] + ssq[1] + ssq[2] + ssq[3];
  float mean = s * (1.0f / CC);
  float var = (sq - (float)CC * mean * mean) * (1.0f / (CC - 1));
  float inv = 1.0f / (sqrtf(fmaxf(var, 0.0f)) + 1e-6f);
  float4 gv = ((const float4*)g)[tid];
  float4 bv = ((const float4*)b)[tid];
  ushort4 o;
  o.x = f2bf(gv.x * (v.x - mean) * inv + bv.x);
  o.y = f2bf(gv.y * (v.y - mean) * inv + bv.y);
  o.z = f2bf(gv.z * (v.z - mean) * inv + bv.z);
  o.w = f2bf(gv.w * (v.w - mean) * inv + bv.w);
  ((ushort4*)(out + (size_t)row * CC))[tid] = o;
}

// ---------------- GEMM (m97-style): out[m,n] = sum_k A[m,k] * W[n,k] ----------------
// Tile BM x 128, BK=64, global_load_lds width-16 staging, XOR-swizzled unpadded LDS.
// lda = row stride of A and W (elements); K = iteration extent; blockIdx.z (split-K)
// offsets the k-range by z*K and (MODE 3) the output by z*M*N.
// MODE 0: qkv epilogue -> bf16 out, scale cols<1024 by 0.125 (q pre-scale), no bias
// MODE 1: + bias + fp32 residual -> fp32 out
// MODE 2: + bias, relu -> bf16 out
// MODE 3: raw fp32 partial -> outf + z*M*N (split-K)
template <int BM, int MODE>
__global__ __launch_bounds__(256) void gemm_bt(const u16* __restrict__ A,
                                               const u16* __restrict__ W,
                                               const float* __restrict__ bias,
                                               const float* __restrict__ resid,
                                               float* __restrict__ outf,
                                               u16* __restrict__ outb,
                                               int M, int N, int K, int lda) {
  constexpr int MI = BM / 32;          // acc rows per wave: 4 (BM=128) or 2 (BM=64)
  __shared__ u16 a_lds[BM * 64];
  __shared__ u16 b_lds[128 * 64];
  int tid = threadIdx.x;
  int w = tid >> 6, lane = tid & 63;
  int l15 = lane & 15, quad = lane >> 4;
  int wm = (w >> 1) * (MI * 16), wn = (w & 1) * 64;
  int tm = blockIdx.x * BM, tn = blockIdx.y * 128;
  size_t koff = (size_t)blockIdx.z * K;
  floatx4 acc[MI][4];
#pragma unroll
  for (int i = 0; i < MI; i++)
#pragma unroll
    for (int j = 0; j < 4; j++) acc[i][j] = (floatx4){0.f, 0.f, 0.f, 0.f};

  // staging: wave w covers BM/4 rows (A) / 32 rows (B); 8 rows per glds16 issue
  int rsub = lane >> 3;              // 0..7
  int cg = (lane & 7) ^ rsub;        // global 16B-chunk index (swizzled)
  const u16* Ag = A + (size_t)(tm + w * (BM / 4) + rsub) * lda + koff + cg * 8;
  const u16* Bg = W + (size_t)(tn + w * 32 + rsub) * lda + koff + cg * 8;
  u16* aL = a_lds + w * (BM / 4) * 64;
  u16* bL = b_lds + w * 32 * 64;

  // fragment read offsets (u16 units); LDS[r][cl] holds G[r][cl ^ (r&7)]
  int x = l15 & 7;
  int offA[MI], offB[4];
#pragma unroll
  for (int i = 0; i < MI; i++) offA[i] = (wm + i * 16 + l15) * 64 + ((quad ^ x) * 8);
#pragma unroll
  for (int j = 0; j < 4; j++) offB[j] = (wn + j * 16 + l15) * 64 + ((quad ^ x) * 8);

  for (int k0 = 0; k0 < K; k0 += 64) {
    __syncthreads();  // prior iter's readers done before overwrite
#pragma unroll
    for (int is = 0; is < BM / 32; is++) glds16(Ag + k0 + (size_t)is * 8 * lda, aL + is * 512);
#pragma unroll
    for (int is = 0; is < 4; is++) glds16(Bg + k0 + (size_t)is * 8 * lda, bL + is * 512);
    __syncthreads();  // drains vmcnt -> tiles resident
#pragma unroll
    for (int s = 0; s < 2; s++) {
      short8 af[MI], bw[4];
#pragma unroll
      for (int i = 0; i < MI; i++) af[i] = *(const short8*)(a_lds + (offA[i] ^ (s << 5)));
#pragma unroll
      for (int j = 0; j < 4; j++) bw[j] = *(const short8*)(b_lds + (offB[j] ^ (s << 5)));
#pragma unroll
      for (int i = 0; i < MI; i++)
#pragma unroll
        for (int j = 0; j < 4; j++)
          acc[i][j] = __builtin_amdgcn_mfma_f32_16x16x32_bf16(af[i], bw[j], acc[i][j], 0, 0, 0);
    }
  }

  float* po = (MODE == 3) ? outf + (size_t)blockIdx.z * M * N : outf;
#pragma unroll
  for (int i = 0; i < MI; i++) {
    int row0 = tm + wm + i * 16 + quad * 4;
#pragma unroll
    for (int j = 0; j < 4; j++) {
      int col = tn + wn + j * 16 + l15;
      float bb = (MODE == 1 || MODE == 2) ? bias[col] : 0.0f;
#pragma unroll
      for (int r = 0; r < 4; r++) {
        int row = row0 + r;
        float v = acc[i][j][r];
        if (MODE == 0) {
          if (col < 1024) v *= 0.125f;
          outb[(size_t)row * N + col] = f2bf(v);
        } else if (MODE == 1) {
          outf[(size_t)row * N + col] = v + bb + resid[(size_t)row * N + col];
        } else if (MODE == 2) {
          outb[(size_t)row * N + col] = f2bf(fmaxf(v + bb, 0.0f));
        } else {
          po[(size_t)row * N + col] = v;
        }
      }
    }
  }
}

// ---------------- split-K reduce: out = p0 + p1 + bias + resid (fp32) ----------------
__global__ __launch_bounds__(256) void reduce2_kernel(const float* __restrict__ p,
                                                      const float* __restrict__ bias,
                                                      const float* __restrict__ resid,
                                                      float* __restrict__ out) {
  int i = blockIdx.x * 256 + threadIdx.x;           // float4 index, 4096*256 = 1M
  float4 a = ((const float4*)p)[i];
  float4 b = ((const float4*)p)[i + 1048576];
  float4 r = ((const float4*)resid)[i];
  float4 bb = ((const float4*)bias)[i & 255];
  float4 o;
  o.x = a.x + b.x + r.x + bb.x;
  o.y = a.y + b.y + r.y + bb.y;
  o.z = a.z + b.z + r.z + bb.z;
  o.w = a.w + b.w + r.w + bb.w;
  ((float4*)out)[i] = o;
}

// ---------------- Flash attention (causal), S^T formulation, 128-key tiles -------
// qkv: [b*T + t][3072] bf16; q (pre-scaled 0.125) cols [0,1024), k [1024,2048), v [2048,3072).
// Block = 64 q-rows x (b,h); 4 waves x 16 q-rows; KV tile = 128 keys.
// S^T = mfma(A=K-frag, B=Q-frag): lane l15 = q-row m, i*16 + quad*4+r = key s.
__global__ __launch_bounds__(256) void flash_kernel(const u16* __restrict__ qkv,
                                                    u16* __restrict__ attn) {
  int bid = blockIdx.x;
  int qt = 31 - (bid >> 5);   // long blocks first
  int bh = bid & 31;
  int b = bh >> 4, h = bh & 15;
  int tid = threadIdx.x, w = tid >> 6, lane = tid & 63;
  int l15 = lane & 15, quad = lane >> 4;

  __shared__ u16 k_lds[128 * 64];       // chunk-swizzled, unpadded (global_load_lds)
  __shared__ u16 vt_lds[64 * 136];      // V^T: [d][s], stride 136 (128 + 8 pad)
  __shared__ u16 p_lds[4][16 * 136];    // per-wave P: [m][s], stride 136

  int qbase = qt * 64 + w * 16;
  const u16* qp = qkv + (size_t)(b * TT + qbase + l15) * 3072 + h * 64;
  short8 qf0 = *(const short8*)(qp + quad * 8);
  short8 qf1 = *(const short8*)(qp + 32 + quad * 8);

  float m_i = -3.0e38f, l_i = 0.0f;
  floatx4 accO[4];
#pragma unroll
  for (int jf = 0; jf < 4; jf++) accO[jf] = (floatx4){0.f, 0.f, 0.f, 0.f};

  // K staging (global_load_lds): wave w rows [w*32, w*32+32), 4 issues of 8 rows
  int rsub = lane >> 3;
  int cg = (lane & 7) ^ rsub;
  const u16* Kg = qkv + (size_t)(b * TT + w * 32 + rsub) * 3072 + 1024 + h * 64 + cg * 8;
  u16* kL = k_lds + w * 32 * 64;
  // V staging with transpose: thread owns 4 s-rows x 8 d's (V is bf16: pure u16 repack)
  int s4 = (tid & 31) * 4;            // s-quad base: 0..124
  int dg = (tid >> 5) * 8;            // d-group: 0..56
  const u16* Vg = qkv + (size_t)(b * TT + s4) * 3072 + 2048 + h * 64 + dg;

  int x = l15 & 7;
  int kOff[8];
#pragma unroll
  for (int i = 0; i < 8; i++) kOff[i] = (i * 16 + l15) * 64 + ((quad ^ x) * 8);
  int pRd = l15 * 136 + quad * 8;

  int nt = (qt + 2) >> 1;               // ceil((qt+1)*64 / 128)
  for (int kt = 0; kt < nt; kt++) {
    int s0 = kt * 128;
    size_t soff = (size_t)s0 * 3072;
    uint4 R0 = *(const uint4*)(Vg + soff);
    uint4 R1 = *(const uint4*)(Vg + soff + 3072);
    uint4 R2 = *(const uint4*)(Vg + soff + 6144);
    uint4 R3 = *(const uint4*)(Vg + soff + 9216);
    __syncthreads();  // prior tile's readers done
#pragma unroll
    for (int is = 0; is < 4; is++) glds16(Kg + soff + (size_t)is * 8 * 3072, kL + is * 512);
    {
      // transpose-pack: vt_lds[d][s4..s4+3] = V[s4..s4+3][d], b64 writes, no same-dword sharing
      unsigned int a0[4] = {R0.x, R0.y, R0.z, R0.w};
      unsigned int a1[4] = {R1.x, R1.y, R1.z, R1.w};
      unsigned int a2[4] = {R2.x, R2.y, R2.z, R2.w};
      unsigned int a3[4] = {R3.x, R3.y, R3.z, R3.w};
#pragma unroll
      for (int p = 0; p < 4; p++) {
        uint2 ev, od;
        ev.x = (a0[p] & 0xffffu) | (a1[p] << 16);
        ev.y = (a2[p] & 0xffffu) | (a3[p] << 16);
        od.x = (a0[p] >> 16) | (a1[p] & 0xffff0000u);
        od.y = (a2[p] >> 16) | (a3[p] & 0xffff0000u);
        *(uint2*)(vt_lds + (dg + 2 * p) * 136 + s4) = ev;
        *(uint2*)(vt_lds + (dg + 2 * p + 1) * 136 + s4) = od;
      }
    }
    __syncthreads();  // drains vmcnt: K resident; vt visible

    // S^T = K * Q^T  (8 key-subtiles of 16)
    floatx4 st[8];
#pragma unroll
    for (int i = 0; i < 8; i++) st[i] = (floatx4){0.f, 0.f, 0.f, 0.f};
#pragma unroll
    for (int i = 0; i < 8; i++) {
      short8 kf0 = *(const short8*)(k_lds + kOff[i]);
      short8 kf1 = *(const short8*)(k_lds + (kOff[i] ^ 32));
      st[i] = __builtin_amdgcn_mfma_f32_16x16x32_bf16(kf0, qf0, st[i], 0, 0, 0);
      st[i] = __builtin_amdgcn_mfma_f32_16x16x32_bf16(kf1, qf1, st[i], 0, 0, 0);
    }

    // causal mask (wave-uniform branch; only tiles overlapping the diagonal)
    if (s0 + 127 > qbase) {
      int mg = qbase + l15;
#pragma unroll
      for (int i = 0; i < 8; i++)
#pragma unroll
        for (int r = 0; r < 4; r++) {
          int s = s0 + i * 16 + quad * 4 + r;
          if (s > mg) st[i][r] = -3.0e38f;
        }
    }

    // online softmax: lane owns one q-row (m = l15); 32 keys in-lane x 4 quads
    float mx = st[0][0];
#pragma unroll
    for (int i = 0; i < 8; i++)
#pragma unroll
      for (int r = 0; r < 4; r++) mx = fmaxf(mx, st[i][r]);
    mx = fmaxf(mx, __shfl_xor(mx, 16));
    mx = fmaxf(mx, __shfl_xor(mx, 32));
    float mnew = fmaxf(m_i, mx);
    float alpha = __expf(m_i - mnew);
    float ts = 0.0f;
#pragma unroll
    for (int i = 0; i < 8; i++)
#pragma unroll
      for (int r = 0; r < 4; r++) {
        float p = __expf(st[i][r] - mnew);
        st[i][r] = p;
        ts += p;
      }
    ts += __shfl_xor(ts, 16);
    ts += __shfl_xor(ts, 32);
    l_i = l_i * alpha + ts;
    m_i = mnew;

    // rescale accO: its rows are m = quad*4+r -> fetch those rows' alpha
    float aR[4];
#pragma unroll
    for (int r = 0; r < 4; r++) aR[r] = __shfl(alpha, quad * 4 + r);
#pragma unroll
    for (int jf = 0; jf < 4; jf++)
#pragma unroll
      for (int r = 0; r < 4; r++) accO[jf][r] *= aR[r];

    // P^T (C-layout) -> p_lds[m][s] with packed b64 writes
#pragma unroll
    for (int i = 0; i < 8; i++) {
      uint2 pk;
      pk.x = pk2bf(st[i][0], st[i][1]);
      pk.y = pk2bf(st[i][2], st[i][3]);
      *(uint2*)(p_lds[w] + l15 * 136 + i * 16 + quad * 4) = pk;
    }

    // PV: O[m][d] += P[m][s] * V^T[d][s], K-dim = 128 keys = 4 chunks of 32
    short8 pf[4];
#pragma unroll
    for (int c = 0; c < 4; c++) pf[c] = *(const short8*)(p_lds[w] + pRd + c * 32);
#pragma unroll
    for (int jf = 0; jf < 4; jf++) {
      int vOff = (jf * 16 + l15) * 136 + quad * 8;
#pragma unroll
      for (int c = 0; c < 4; c++) {
        short8 vf = *(const short8*)(vt_lds + vOff + c * 32);
        accO[jf] = __builtin_amdgcn_mfma_f32_16x16x32_bf16(pf[c], vf, accO[jf], 0, 0, 0);
      }
    }
  }

  // epilogue: accO rows m = quad*4+r, cols d = jf*16+l15; 1/l per row via shuffle
  float invl = 1.0f / l_i;
  float iR[4];
#pragma unroll
  for (int r = 0; r < 4; r++) iR[r] = __shfl(invl, quad * 4 + r);
  int orow = b * TT + qbase + quad * 4;
#pragma unroll
  for (int r = 0; r < 4; r++) {
    u16* op = attn + (size_t)(orow + r) * CC + h * 64 + l15;
#pragma unroll
    for (int jf = 0; jf < 4; jf++) op[jf * 16] = f2bf(accO[jf][r] * iR[r]);
  }
}

// ---------------- launch ----------------
extern "C" void kernel_launch(void* const* d_in, const int* in_sizes, int n_in,
                              void* d_out, int out_size, void* d_ws, size_t ws_size,
                              hipStream_t stream) {
  const float* x      = (const float*)d_in[0];
  const float* qkv_w  = (const float*)d_in[1];
  const float* proj_w = (const float*)d_in[2];
  const float* proj_b = (const float*)d_in[3];
  const float* l1_w   = (const float*)d_in[4];
  const float* l1_b   = (const float*)d_in[5];
  const float* l3_w   = (const float*)d_in[6];
  const float* l3_b   = (const float*)d_in[7];
  const float* ln1_g  = (const float*)d_in[8];
  const float* ln1_b  = (const float*)d_in[9];
  const float* ln2_g  = (const float*)d_in[10];
  const float* ln2_b  = (const float*)d_in[11];
  float* out = (float*)d_out;
  char* ws = (char*)d_ws;

  u16* w_qkv  = (u16*)(ws + 0);
  u16* w_proj = (u16*)(ws + 6291456);
  u16* w_l1   = (u16*)(ws + 8388608);
  u16* w_l3   = (u16*)(ws + 16777216);
  u16* lnb    = (u16*)(ws + 25165824);
  u16* qkvb   = (u16*)(ws + 33554432);
  u16* attnb  = (u16*)(ws + 58720256);
  float* x1   = (float*)(ws + 67108864);
  u16* hb     = (u16*)(ws + 83886080);
  // l3 split-K partials reuse dead qkvb+attnb region: [33554432, 67108864) = 2 x 16.8 MB
  float* l3p  = (float*)(ws + 33554432);

  cvt_all_kernel<<<12288, 256, 0, stream>>>(qkv_w, proj_w, l1_w, l3_w,
                                            w_qkv, w_proj, w_l1, w_l3);

  ln_kernel<<<4096, 256, 0, stream>>>(x, ln1_g, ln1_b, lnb);
  gemm_bt<128, 0><<<dim3(32, 24), 256, 0, stream>>>(lnb, w_qkv, nullptr, nullptr, nullptr,
                                                    qkvb, 4096, 3072, 1024, 1024);
  flash_kernel<<<1024, 256, 0, stream>>>(qkvb, attnb);
  gemm_bt<64, 1><<<dim3(64, 8), 256, 0, stream>>>(attnb, w_proj, proj_b, x, x1, nullptr,
                                                  4096, 1024, 1024, 1024);
  ln_kernel<<<4096, 256, 0, stream>>>(x1, ln2_g, ln2_b, lnb);
  gemm_bt<128, 2><<<dim3(32, 32), 256, 0, stream>>>(lnb, w_l1, l1_b, nullptr, nullptr, hb,
                                                    4096, 4096, 1024, 1024);
  // l3: split-K=2 over K=4096 (each z does K=2048), partials -> l3p, then fused reduce
  gemm_bt<64, 3><<<dim3(64, 8, 2), 256, 0, stream>>>(hb, w_l3, nullptr, nullptr, l3p,
                                                     nullptr, 4096, 1024, 2048, 4096);
  reduce2_kernel<<<4096, 256, 0, stream>>>(l3p, l3_b, x1, out);
}